// Round 3
// baseline (95.713 us; speedup 1.0000x reference)
//
#include <hip/hip_runtime.h>
#include <math.h>

static constexpr int   B    = 256;   // batch
static constexpr int   D    = 256;   // feature dim
static constexpr int   NSV  = 512;   // P == Q
static constexpr int   RG   = 16;    // SV row-groups
static constexpr int   RPS  = NSV / RG;   // 32 rows per set per block
static constexpr int   RPB  = 2 * RPS;    // 64 tile rows (set1 then set0)
static constexpr int   NB   = 8;          // batches per block
static constexpr int   NT   = 128;        // 2 waves
static constexpr int   KC   = 64;         // chunk (floats per row)
static constexpr int   NCH  = D / KC;     // 4 chunks
static constexpr int   SPR  = KC / 4;     // 16 f4 slots per row
static constexpr float G    = 0.1f;
static constexpr float CSH  = 26.0f;      // fixed LSE shift; cancels in LSE0-LSE1

__device__ __forceinline__ void gld16(const void* g, void* l) {
    __builtin_amdgcn_global_load_lds((__attribute__((address_space(1))) void*)g,
                                     (__attribute__((address_space(3))) void*)l,
                                     16, 0, 0);
}

__global__ __launch_bounds__(NT)
void k_partial(const float* __restrict__ x,
               const float* __restrict__ sv1,
               const float* __restrict__ sv0,
               const float* __restrict__ a1,
               const float* __restrict__ a0,
               float* __restrict__ ws)
{
    __shared__ float tile[3][RPB * KC];   // 3 x 16 KiB SV chunk buffers
    __shared__ float xs[NB * D];          // 8 KiB staged x rows

    const int t     = threadIdx.x;
    const int rg    = blockIdx.x;
    const int bbase = blockIdx.y * NB;
    const int r     = t & (RPB - 1);      // tile row owned by this thread
    const int bg    = t >> 6;             // batch-group (wave-uniform): 0 or 1

    // ---- stage x rows (linear, 4 slots/thread) ----
    {
        const float* xsrc = x + (size_t)bbase * D;
        #pragma unroll
        for (int i = 0; i < (NB * D / 4) / NT; ++i) {   // 4
            const int f = i * NT + t;
            gld16(xsrc + f * 4, &xs[f * 4]);
        }
    }

    // ---- SV chunk staging: linear LDS dest, XOR-swizzled global source ----
    auto stage = [&](int c, float* buf) {
        #pragma unroll
        for (int i = 0; i < (RPB * KC / 4) / NT; ++i) { // 8 slots/thread
            const int f  = i * NT + t;
            const int rr = f >> 4;          // tile row
            const int p  = f & 15;          // physical f4 slot
            const int q  = p ^ (rr & 7);    // logical slot (involution)
            const float* src = (rr < RPS)
                ? (sv1 + (size_t)(rg * RPS + rr) * D)
                : (sv0 + (size_t)(rg * RPS + (rr - RPS)) * D);
            gld16(src + c * KC + q * 4, buf + f * 4);
        }
    };

    float ssq = 0.f, d0 = 0.f, d1 = 0.f, d2 = 0.f, d3 = 0.f;

    auto compute = [&](int cc, const float* buf) {
        const float4* tf = reinterpret_cast<const float4*>(buf);
        const float4* xf = reinterpret_cast<const float4*>(xs) + cc * SPR;
        #pragma unroll
        for (int kk = 0; kk < SPR; ++kk) {
            const int p = kk ^ (r & 7);                 // de-swizzle
            const float4 s4 = tf[(r << 4) + p];
            const float4 x0 = xf[(bg * 4 + 0) * (D / 4) + kk];
            const float4 x1 = xf[(bg * 4 + 1) * (D / 4) + kk];
            const float4 x2 = xf[(bg * 4 + 2) * (D / 4) + kk];
            const float4 x3 = xf[(bg * 4 + 3) * (D / 4) + kk];
            ssq = fmaf(s4.x, s4.x, ssq); ssq = fmaf(s4.y, s4.y, ssq);
            ssq = fmaf(s4.z, s4.z, ssq); ssq = fmaf(s4.w, s4.w, ssq);
            d0 = fmaf(s4.x, x0.x, d0); d0 = fmaf(s4.y, x0.y, d0);
            d0 = fmaf(s4.z, x0.z, d0); d0 = fmaf(s4.w, x0.w, d0);
            d1 = fmaf(s4.x, x1.x, d1); d1 = fmaf(s4.y, x1.y, d1);
            d1 = fmaf(s4.z, x1.z, d1); d1 = fmaf(s4.w, x1.w, d1);
            d2 = fmaf(s4.x, x2.x, d2); d2 = fmaf(s4.y, x2.y, d2);
            d2 = fmaf(s4.z, x2.z, d2); d2 = fmaf(s4.w, x2.w, d2);
            d3 = fmaf(s4.x, x3.x, d3); d3 = fmaf(s4.y, x3.y, d3);
            d3 = fmaf(s4.z, x3.z, d3); d3 = fmaf(s4.w, x3.w, d3);
        }
    };

    // prefetch depth 2: x(4) + c0(8) + c1(8) + c2(8) in flight
    stage(0, tile[0]);
    stage(1, tile[1]);
    stage(2, tile[2]);

    asm volatile("s_waitcnt vmcnt(16)" ::: "memory");  // x + c0 done
    __builtin_amdgcn_s_barrier();
    __builtin_amdgcn_sched_barrier(0);
    compute(0, tile[0]);
    __builtin_amdgcn_s_barrier();                      // both waves done reading buf0
    stage(3, tile[0]);

    asm volatile("s_waitcnt vmcnt(16)" ::: "memory");  // c1 done (c2,c3 in flight)
    __builtin_amdgcn_s_barrier();
    __builtin_amdgcn_sched_barrier(0);
    compute(1, tile[1]);

    asm volatile("s_waitcnt vmcnt(8)" ::: "memory");   // c2 done
    __builtin_amdgcn_s_barrier();
    __builtin_amdgcn_sched_barrier(0);
    compute(2, tile[2]);

    asm volatile("s_waitcnt vmcnt(0)" ::: "memory");   // c3 done
    __builtin_amdgcn_s_barrier();
    __builtin_amdgcn_sched_barrier(0);
    compute(3, tile[0]);

    // ---- epilogue: score -> exp -> per-set 32-lane reduction ----
    const int   rloc = r & (RPS - 1);
    const int   set  = r >> 5;            // 0 = sv1 rows, 1 = sv0 rows
    const float av   = set ? a0[rg * RPS + rloc] : a1[rg * RPS + rloc];
    const float lal  = logf(av);

    float e0 = __expf(G * (ssq - 2.f * d0) - lal - CSH);
    float e1 = __expf(G * (ssq - 2.f * d1) - lal - CSH);
    float e2 = __expf(G * (ssq - 2.f * d2) - lal - CSH);
    float e3 = __expf(G * (ssq - 2.f * d3) - lal - CSH);

    #pragma unroll
    for (int off = 16; off > 0; off >>= 1) {   // reduce within 32-lane halves
        e0 += __shfl_xor(e0, off);
        e1 += __shfl_xor(e1, off);
        e2 += __shfl_xor(e2, off);
        e3 += __shfl_xor(e3, off);
    }
    const int l = t & 63;
    if (l == 0 || l == 32) {
        float* dst = ws + (size_t)set * (RG * B) + rg * B + bbase + bg * 4;
        dst[0] = e0; dst[1] = e1; dst[2] = e2; dst[3] = e3;
    }
}

// out[b] = log(S0) - log(S1); the CSH shift cancels exactly.
__global__ __launch_bounds__(B)
void k_final(const float* __restrict__ ws, float* __restrict__ out)
{
    const int b = threadIdx.x;
    float S1 = 0.f, S0 = 0.f;
    #pragma unroll
    for (int rg = 0; rg < RG; ++rg) {
        S1 += ws[rg * B + b];
        S0 += ws[RG * B + rg * B + b];
    }
    out[b] = logf(S0) - logf(S1);
}

extern "C" void kernel_launch(void* const* d_in, const int* in_sizes, int n_in,
                              void* d_out, int out_size, void* d_ws, size_t ws_size,
                              hipStream_t stream) {
    const float* x   = (const float*)d_in[0];
    const float* sv1 = (const float*)d_in[1];
    const float* sv0 = (const float*)d_in[2];
    const float* a1  = (const float*)d_in[3];
    const float* a0  = (const float*)d_in[4];
    float* ws  = (float*)d_ws;
    float* out = (float*)d_out;

    dim3 g1(RG, B / NB);   // 16 x 32 = 512 blocks
    k_partial<<<g1, NT, 0, stream>>>(x, sv1, sv0, a1, a0, ws);
    k_final<<<1, B, 0, stream>>>(ws, out);
}

// Round 4
// 14.149 us; speedup vs baseline: 6.7647x; 6.7647x over previous
//
#include <hip/hip_runtime.h>
#include <math.h>

static constexpr int   B    = 256;   // batch
static constexpr int   D    = 256;   // feature dim
static constexpr int   NSV  = 512;   // P == Q
static constexpr int   RG   = 16;    // SV row-groups
static constexpr int   RPS  = NSV / RG;   // 32 rows per set per block
static constexpr int   RPB  = 2 * RPS;    // 64 tile rows (set1 then set0)
static constexpr int   NB   = 8;          // batches per block (2 waves x 4)
static constexpr int   NT   = 128;        // 2 waves
static constexpr int   KC   = 64;         // chunk (floats per row)
static constexpr int   SPR  = KC / 4;     // 16 f4 slots per row
static constexpr float G    = 0.1f;
static constexpr float CSH  = 26.0f;      // fixed LSE shift; cancels in LSE0-LSE1

typedef float f32x2 __attribute__((ext_vector_type(2)));

__device__ __forceinline__ void gld16(const void* g, void* l) {
    __builtin_amdgcn_global_load_lds((__attribute__((address_space(1))) void*)g,
                                     (__attribute__((address_space(3))) void*)l,
                                     16, 0, 0);
}

__global__ __launch_bounds__(NT)
void k_partial(const float* __restrict__ x,
               const float* __restrict__ sv1,
               const float* __restrict__ sv0,
               const float* __restrict__ a1,
               const float* __restrict__ a0,
               float* __restrict__ ws)
{
    __shared__ float tile[2][RPB * KC];   // 2 x 16 KiB SV chunk buffers

    const int t     = threadIdx.x;
    const int rg    = blockIdx.x;
    const int bbase = blockIdx.y * NB;
    const int r     = t & (RPB - 1);      // tile row owned by this thread
    // wave-uniform batch-group -> x addresses become SGPR (scalar loads)
    const int bgu   = __builtin_amdgcn_readfirstlane(t >> 6);
    const float* xw = x + (size_t)(bbase + bgu * 4) * D;

    // SV chunk staging: linear LDS dest, XOR-swizzled global source (involution)
    auto stage = [&](int c, int buf) {
        #pragma unroll
        for (int i = 0; i < (RPB * SPR) / NT; ++i) {   // 8 slots/thread
            const int f  = i * NT + t;
            const int rr = f >> 4;          // tile row
            const int p  = f & 15;          // physical f4 slot
            const int q  = p ^ (rr & 7);    // logical slot
            const float* src = (rr < RPS)
                ? (sv1 + (size_t)(rg * RPS + rr) * D)
                : (sv0 + (size_t)(rg * RPS + (rr - RPS)) * D);
            gld16(src + c * KC + q * 4, &tile[buf][f * 4]);
        }
    };

    f32x2 ssq = {0.f, 0.f};
    f32x2 d0 = {0.f, 0.f}, d1 = {0.f, 0.f}, d2 = {0.f, 0.f}, d3 = {0.f, 0.f};

    auto compute = [&](int cc, int buf) {
        const float4* tf = reinterpret_cast<const float4*>(&tile[buf][0]);
        const float*  xc = xw + cc * KC;
        #pragma unroll 4
        for (int kk = 0; kk < SPR; ++kk) {
            const int p = kk ^ (r & 7);                 // de-swizzle
            const float4 s4 = tf[(r << 4) + p];
            const f32x2 sa = {s4.x, s4.y};
            const f32x2 sb = {s4.z, s4.w};
            const float4 x0 = *reinterpret_cast<const float4*>(xc + 0 * D + kk * 4);
            const float4 x1 = *reinterpret_cast<const float4*>(xc + 1 * D + kk * 4);
            const float4 x2 = *reinterpret_cast<const float4*>(xc + 2 * D + kk * 4);
            const float4 x3 = *reinterpret_cast<const float4*>(xc + 3 * D + kk * 4);
            ssq = __builtin_elementwise_fma(sa, sa, ssq);
            ssq = __builtin_elementwise_fma(sb, sb, ssq);
            d0 = __builtin_elementwise_fma(sa, (f32x2){x0.x, x0.y}, d0);
            d0 = __builtin_elementwise_fma(sb, (f32x2){x0.z, x0.w}, d0);
            d1 = __builtin_elementwise_fma(sa, (f32x2){x1.x, x1.y}, d1);
            d1 = __builtin_elementwise_fma(sb, (f32x2){x1.z, x1.w}, d1);
            d2 = __builtin_elementwise_fma(sa, (f32x2){x2.x, x2.y}, d2);
            d2 = __builtin_elementwise_fma(sb, (f32x2){x2.z, x2.w}, d2);
            d3 = __builtin_elementwise_fma(sa, (f32x2){x3.x, x3.y}, d3);
            d3 = __builtin_elementwise_fma(sb, (f32x2){x3.z, x3.w}, d3);
        }
    };

    // depth-2 prefetch pipeline over 4 chunks, counted vmcnt
    stage(0, 0);
    stage(1, 1);

    asm volatile("s_waitcnt vmcnt(8)" ::: "memory");   // c0 done
    __builtin_amdgcn_s_barrier();
    __builtin_amdgcn_sched_barrier(0);
    compute(0, 0);
    __builtin_amdgcn_sched_barrier(0);
    __builtin_amdgcn_s_barrier();                      // both waves done with buf0
    stage(2, 0);

    asm volatile("s_waitcnt vmcnt(8)" ::: "memory");   // c1 done
    __builtin_amdgcn_s_barrier();
    __builtin_amdgcn_sched_barrier(0);
    compute(1, 1);
    __builtin_amdgcn_sched_barrier(0);
    __builtin_amdgcn_s_barrier();                      // both waves done with buf1
    stage(3, 1);

    asm volatile("s_waitcnt vmcnt(8)" ::: "memory");   // c2 done
    __builtin_amdgcn_s_barrier();
    __builtin_amdgcn_sched_barrier(0);
    compute(2, 0);

    asm volatile("s_waitcnt vmcnt(0)" ::: "memory");   // c3 done
    __builtin_amdgcn_s_barrier();
    __builtin_amdgcn_sched_barrier(0);
    compute(3, 1);

    // ---- epilogue: score -> exp -> per-set 32-lane reduction ----
    const int   rloc = r & (RPS - 1);
    const int   set  = r >> 5;            // 0 = sv1 rows, 1 = sv0 rows
    const float av   = set ? a0[rg * RPS + rloc] : a1[rg * RPS + rloc];
    const float lal  = logf(av);
    const float sq   = ssq.x + ssq.y;

    float e0 = __expf(G * (sq - 2.f * (d0.x + d0.y)) - lal - CSH);
    float e1 = __expf(G * (sq - 2.f * (d1.x + d1.y)) - lal - CSH);
    float e2 = __expf(G * (sq - 2.f * (d2.x + d2.y)) - lal - CSH);
    float e3 = __expf(G * (sq - 2.f * (d3.x + d3.y)) - lal - CSH);

    #pragma unroll
    for (int off = 16; off > 0; off >>= 1) {   // reduce within 32-lane halves
        e0 += __shfl_xor(e0, off);
        e1 += __shfl_xor(e1, off);
        e2 += __shfl_xor(e2, off);
        e3 += __shfl_xor(e3, off);
    }
    const int l = t & 63;
    const int bg = t >> 6;
    if (l == 0 || l == 32) {
        float* dst = ws + (size_t)set * (RG * B) + rg * B + bbase + bg * 4;
        dst[0] = e0; dst[1] = e1; dst[2] = e2; dst[3] = e3;
    }
}

// out[b] = log(S0) - log(S1); the CSH shift cancels exactly.
__global__ __launch_bounds__(B)
void k_final(const float* __restrict__ ws, float* __restrict__ out)
{
    const int b = threadIdx.x;
    float S1 = 0.f, S0 = 0.f;
    #pragma unroll
    for (int rg = 0; rg < RG; ++rg) {
        S1 += ws[rg * B + b];
        S0 += ws[RG * B + rg * B + b];
    }
    out[b] = logf(S0) - logf(S1);
}

extern "C" void kernel_launch(void* const* d_in, const int* in_sizes, int n_in,
                              void* d_out, int out_size, void* d_ws, size_t ws_size,
                              hipStream_t stream) {
    const float* x   = (const float*)d_in[0];
    const float* sv1 = (const float*)d_in[1];
    const float* sv0 = (const float*)d_in[2];
    const float* a1  = (const float*)d_in[3];
    const float* a0  = (const float*)d_in[4];
    float* ws  = (float*)d_ws;
    float* out = (float*)d_out;

    dim3 g1(RG, B / NB);   // 16 x 32 = 512 blocks
    k_partial<<<g1, NT, 0, stream>>>(x, sv1, sv0, a1, a0, ws);
    k_final<<<1, B, 0, stream>>>(ws, out);
}